// Round 8
// baseline (661.014 us; speedup 1.0000x reference)
//
#include <hip/hip_runtime.h>
#include <stdint.h>

#define AS1 __attribute__((address_space(1)))
#define AS3 __attribute__((address_space(3)))

typedef __bf16 bf16x8 __attribute__((ext_vector_type(8)));   // 4 VGPRs
typedef float  f32x4  __attribute__((ext_vector_type(4)));
typedef float  f32x16 __attribute__((ext_vector_type(16)));

#define MFMA16(a, b, c) __builtin_amdgcn_mfma_f32_16x16x32_bf16((a), (b), (c), 0, 0, 0)
#define MFMA32(a, b, c) __builtin_amdgcn_mfma_f32_32x32x16_bf16((a), (b), (c), 0, 0, 0)

// ---- constants for this problem ----
#define SEQ   512
#define NBAT  64
#define DM    768
#define NH    12
#define DH    64
#define NQKV  2304
#define NTOK  (NBAT * SEQ)   // 32768

__device__ __forceinline__ uint16_t f2bf(float x) {          // fp32 -> bf16 RNE
  uint32_t u = __float_as_uint(x);
  return (uint16_t)((u + 0x7FFFu + ((u >> 16) & 1u)) >> 16);
}

__device__ __forceinline__ void async16(uint16_t* lds, const uint16_t* g) {
  // 16B global -> LDS direct (dest = wave-uniform base + lane*16)
  __builtin_amdgcn_global_load_lds((AS1 void*)(uintptr_t)(const void*)g,
                                   (AS3 void*)lds, 16, 0, 0);
}

// row->column XOR swizzle: conflict-free for 16/32-row MFMA fragment reads
// (verified: R5 GEMM conflicts 1.4e7 -> 0).
__device__ __forceinline__ int swz(int r) { return (r ^ (r >> 3)) & 7; }

// ---------------- merged converter (tokens + weights + biases) ----------------
__global__ __launch_bounds__(256) void k_cvt(
    const float* __restrict__ tokens,
    const float* __restrict__ Wq, const float* __restrict__ Wk,
    const float* __restrict__ Wv, const float* __restrict__ Wo,
    const float* __restrict__ bq, const float* __restrict__ bk, const float* __restrict__ bv,
    uint16_t* __restrict__ X, uint16_t* __restrict__ Wqkv, uint16_t* __restrict__ Wob,
    float* __restrict__ bqkv) {
  int i = blockIdx.x * 256 + threadIdx.x;     // grid covers NTOK*DM/8 = 3,145,728
  {
    const float4* sp = (const float4*)tokens;
    float4 a = sp[2 * i], b = sp[2 * i + 1];
    union { uint16_t u[8]; uint4 v; } o;
    o.u[0] = f2bf(a.x); o.u[1] = f2bf(a.y); o.u[2] = f2bf(a.z); o.u[3] = f2bf(a.w);
    o.u[4] = f2bf(b.x); o.u[5] = f2bf(b.y); o.u[6] = f2bf(b.z); o.u[7] = f2bf(b.w);
    ((uint4*)X)[i] = o.v;
  }
  if (i < 589824) {
    Wqkv[i]              = f2bf(Wq[i]);
    Wqkv[i + 589824]     = f2bf(Wk[i]);
    Wqkv[i + 2 * 589824] = f2bf(Wv[i]);
    Wob[i]               = f2bf(Wo[i]);
    if (i < 768) { bqkv[i] = bq[i]; bqkv[i + 768] = bk[i]; bqkv[i + 1536] = bv[i]; }
  }
}

// ---------------- GEMM: C[M,N] = A[M,K] * B[N,K]^T + bias(col), optional *rowscale(row) ----------------
// 128x128 tile, BK=64, 4 waves (2x2 of 64x64), 32x32x16 bf16 MFMA.
// A staged in LDS (swizzled, global_load_lds). B fragments loaded DIRECT from
// global into VGPRs (weights are L2-resident) -> LDS traffic per block-iter
// 96KB -> 48KB; B loads issue before the staging barrier so the pre-barrier
// vmcnt(0) drain hides their L2 latency behind A's HBM staging.
// 1D grid, super-tiled: supers of 32 row-tiles x ncol col-tiles.
__global__ __launch_bounds__(256) void k_gemm_bt(
    const uint16_t* __restrict__ A, const uint16_t* __restrict__ B,
    const float* __restrict__ bias, const float* __restrict__ rowscale,
    uint16_t* __restrict__ C, int K, int ldc, int ncol) {
  __shared__ uint16_t Alds[128 * 64];   // 16 KB
  const int tid  = threadIdx.x;
  const int w    = tid >> 6, lane = tid & 63;
  const int wu   = __builtin_amdgcn_readfirstlane(w);
  const int l32  = lane & 31, kh = lane >> 5;
  const int sup  = blockIdx.x / (32 * ncol);
  const int t    = blockIdx.x % (32 * ncol);
  const int row0 = (sup * 32 + (t & 31)) * 128, col0 = (t >> 5) * 128;
  const int wrow = (w >> 1) * 64,   wcol = (w & 1) * 64;

  f32x16 acc[2][2] = {};
  const int nkb = K >> 6;
  const uint16_t* bbase = B + (size_t)(col0 + wcol + l32) * K + kh * 8;
  for (int kb = 0; kb < nkb; ++kb) {
    // B fragments for this K-block: 8 global b128 loads, L2-hits.
    bf16x8 bfr[4][2];
#pragma unroll
    for (int ks = 0; ks < 4; ++ks)
#pragma unroll
      for (int nt = 0; nt < 2; ++nt)
        bfr[ks][nt] = *(const bf16x8*)(bbase + (size_t)nt * 32 * K + kb * 64 + ks * 16);
    __syncthreads();                              // prev iter's A-frag reads done
#pragma unroll
    for (int j = 0; j < 4; ++j) {                 // A: 1024 chunks
      int cid = j * 256 + w * 64 + lane;
      int r = cid >> 3, cc = cid & 7, c = cc ^ swz(r);
      async16(&Alds[(j * 256 + wu * 64) * 8],
              A + (size_t)(row0 + r) * K + kb * 64 + c * 8);
    }
    __syncthreads();                              // staging (and B loads) drained
#pragma unroll
    for (int ks = 0; ks < 4; ++ks) {              // 4 k-steps of 16
      bf16x8 af[2];
#pragma unroll
      for (int mt = 0; mt < 2; ++mt) {
        int r = wrow + mt * 32 + l32;
        int c = (ks * 2 + kh) ^ swz(r);
        af[mt] = *(const bf16x8*)&Alds[r * 64 + c * 8];
      }
#pragma unroll
      for (int mt = 0; mt < 2; ++mt)
#pragma unroll
        for (int nt = 0; nt < 2; ++nt)
          acc[mt][nt] = MFMA32(af[mt], bfr[ks][nt], acc[mt][nt]);
    }
  }
  // epilogue: 32x32 C/D layout: col=lane&31, row=(reg&3)+8*(reg>>2)+4*(lane>>5)
#pragma unroll
  for (int nt = 0; nt < 2; ++nt) {
    int col = col0 + wcol + nt * 32 + l32;
    float bv = bias[col];
#pragma unroll
    for (int mt = 0; mt < 2; ++mt) {
#pragma unroll
      for (int rg = 0; rg < 16; ++rg) {
        int row = row0 + wrow + mt * 32 + (rg & 3) + 8 * (rg >> 2) + 4 * kh;
        float v = acc[mt][nt][rg] + bv;
        if (rowscale) v *= rowscale[row];
        C[(size_t)row * ldc + col] = f2bf(v);
      }
    }
  }
}

// ---------------- fused attention ----------------
// grid = 768 heads * 4 q-tiles (XCD-swizzled); block 256 = 4 waves; wave owns 32 q rows.
// P = exp2(S*c1 - |t~q - t~k|) with t~ = ts*c2 (mask folded: masked key -> t~ = 3e38 -> P = 0).
__global__ __launch_bounds__(256) void k_attn(
    const uint16_t* __restrict__ QKV, const float* __restrict__ ts,
    const float* __restrict__ mask, uint16_t* __restrict__ Aout) {
  __shared__ uint16_t Klds[64 * 64];        // swizzled chunks, 8KB
  __shared__ uint16_t Vt[64 * 72];          // [d][k] padded, 9KB
  __shared__ uint16_t Plds[4][32 * 72];     // per-wave P tile, stride 72, 18KB
  __shared__ float tkl[SEQ];                // ts*c2, masked -> +3e38

  const int tid = threadIdx.x, w = tid >> 6, lane = tid & 63;
  const int wu = __builtin_amdgcn_readfirstlane(w);
  const int quad = lane >> 4, l16 = lane & 15;
  // XCD-aware decode: 4 q-tiles of one head land on one XCD, temporally adjacent
  int b = blockIdx.x;
  int xcd = b & 7, i = b >> 3;
  int qt = i & 3;
  int hg = xcd * 96 + (i >> 2);             // 0..767
  int n = hg / NH, h = hg % NH;
  const int q0 = qt * 128 + w * 32;
  const size_t rowbase = (size_t)n * SEQ * NQKV;

  const float c1 = 0.125f * 1.44269504f;     // scale * log2(e)
  const float c2 = 1.44269504f / 300.0f;     // log2(e) / tau

  for (int l = tid; l < SEQ; l += 256) {
    float t = ts[n * SEQ + l] * c2;
    tkl[l] = (mask[n * SEQ + l] > 0.f) ? t : 3e38f;
  }

  // Q fragments (A-operand): A[m=lane&15][k=quad*8+j]
  bf16x8 qf[2][2];
  float tq[2][4];
#pragma unroll
  for (int qs = 0; qs < 2; ++qs) {
    int qr = q0 + qs * 16 + l16;
    const uint16_t* qp = QKV + rowbase + (size_t)qr * NQKV + h * DH;
#pragma unroll
    for (int dsp = 0; dsp < 2; ++dsp)
      qf[qs][dsp] = *(const bf16x8*)(qp + dsp * 32 + quad * 8);
#pragma unroll
    for (int rg = 0; rg < 4; ++rg)
      tq[qs][rg] = ts[n * SEQ + q0 + qs * 16 + quad * 4 + rg] * c2;
  }

  f32x4 accO[2][4] = {};
  f32x4 accL[2] = {};
  bf16x8 ones_b;
  {
    union { uint16_t u[8]; bf16x8 v; } t;
    uint16_t o = (l16 == 0) ? 0x3F80 : 0;   // bf16 1.0 in column 0 only
#pragma unroll
    for (int j = 0; j < 8; ++j) t.u[j] = o;
    ones_b = t.v;
  }
  uint16_t* Pw = &Plds[w][0];

  for (int k0 = 0; k0 < SEQ; k0 += 64) {
    __syncthreads();
    // stage K rows (row-major 64x64, swz-swizzled) via global_load_lds
#pragma unroll
    for (int j = 0; j < 2; ++j) {
      int cid = j * 256 + w * 64 + lane;      // 0..511
      int r = cid >> 3, cc = cid & 7, c = cc ^ swz(r);
      const uint16_t* g = QKV + rowbase + (size_t)(k0 + r) * NQKV + DM + h * DH + c * 8;
      async16(&Klds[(j * 256 + wu * 64) * 8], g);
    }
    // stage V transposed: Vt[d][k]
    {
      int r = tid & 63, db = (tid >> 6) * 16;
      const uint16_t* g = QKV + rowbase + (size_t)(k0 + r) * NQKV + 2 * DM + h * DH + db;
      union { uint4 v; uint16_t u[8]; } a0, a1;
      a0.v = *(const uint4*)g;
      a1.v = *(const uint4*)(g + 8);
#pragma unroll
      for (int j = 0; j < 8; ++j) Vt[(db + j) * 72 + r] = a0.u[j];
#pragma unroll
      for (int j = 0; j < 8; ++j) Vt[(db + 8 + j) * 72 + r] = a1.u[j];
    }
    __syncthreads();

#pragma unroll
    for (int kt = 0; kt < 2; ++kt) {
      // S = Q K^T over this 32-col k-tile; columns interleaved: n -> k = 2*(lane&15)+ksu
      f32x4 s[2][2] = {};
#pragma unroll
      for (int dsp = 0; dsp < 2; ++dsp) {
        bf16x8 kf[2];
#pragma unroll
        for (int ksu = 0; ksu < 2; ++ksu) {
          int r = kt * 32 + 2 * l16 + ksu;
          int c = (dsp * 4 + quad) ^ swz(r);
          kf[ksu] = *(const bf16x8*)&Klds[r * 64 + c * 8];
        }
#pragma unroll
        for (int qs = 0; qs < 2; ++qs)
#pragma unroll
          for (int ksu = 0; ksu < 2; ++ksu)
            s[qs][ksu] = MFMA16(qf[qs][dsp], kf[ksu], s[qs][ksu]);
      }
      // bias + exp + pack to bf16 pairs -> Plds[q][k] (natural k order)
      float tk0 = tkl[k0 + kt * 32 + 2 * l16];
      float tk1 = tkl[k0 + kt * 32 + 2 * l16 + 1];
#pragma unroll
      for (int qs = 0; qs < 2; ++qs) {
#pragma unroll
        for (int rg = 0; rg < 4; ++rg) {
          float d0 = fabsf(tq[qs][rg] - tk0);   // v_sub; abs/neg ride as fma modifiers
          float d1 = fabsf(tq[qs][rg] - tk1);
          float p0 = __builtin_amdgcn_exp2f(fmaf(s[qs][0][rg], c1, -d0));
          float p1 = __builtin_amdgcn_exp2f(fmaf(s[qs][1][rg], c1, -d1));
          uint32_t u = (__float_as_uint(p0) >> 16) | (__float_as_uint(p1) & 0xFFFF0000u);
          *(uint32_t*)(Pw + (qs * 16 + quad * 4 + rg) * 72 + kt * 32 + 2 * l16) = u;
        }
      }
      // PV (+ ones column for row-sums). Wave-private LDS: per-wave in-order, no barrier.
      bf16x8 vb[4];
#pragma unroll
      for (int dt = 0; dt < 4; ++dt)
        vb[dt] = *(const bf16x8*)&Vt[(dt * 16 + l16) * 72 + kt * 32 + quad * 8];
#pragma unroll
      for (int qs = 0; qs < 2; ++qs) {
        bf16x8 pa = *(const bf16x8*)(Pw + (qs * 16 + l16) * 72 + kt * 32 + quad * 8);
#pragma unroll
        for (int dt = 0; dt < 4; ++dt)
          accO[qs][dt] = MFMA16(pa, vb[dt], accO[qs][dt]);
        accL[qs] = MFMA16(pa, ones_b, accL[qs]);
      }
    }
  }
  // epilogue: O = accO / l ; l lives in column 0 (lane quad*16) of accL
#pragma unroll
  for (int qs = 0; qs < 2; ++qs) {
    float inv[4];
#pragma unroll
    for (int rg = 0; rg < 4; ++rg) {
      float lv = __shfl(accL[qs][rg], lane & 48, 64);
      inv[rg] = 1.0f / lv;
    }
#pragma unroll
    for (int dt = 0; dt < 4; ++dt) {
#pragma unroll
      for (int rg = 0; rg < 4; ++rg) {
        int qr = q0 + qs * 16 + quad * 4 + rg;
        float v = accO[qs][dt][rg] * inv[rg];
        Aout[(size_t)(n * SEQ + qr) * DM + h * DH + dt * 16 + l16] = f2bf(v);
      }
    }
  }
}

// ---------------- readout pooling ----------------
__global__ __launch_bounds__(256) void k_pool(
    const uint16_t* __restrict__ Out, const float* __restrict__ mask,
    const float* __restrict__ readout, float* __restrict__ dst) {
  __shared__ float rsl[64];
  __shared__ float ex[SEQ];
  __shared__ float red[4];
  __shared__ float part[8][64];
  int b = blockIdx.x;
  int n = b / NH, h = b % NH;
  int tid = threadIdx.x;
  if (tid < 64) rsl[tid] = readout[h * DH + tid];
  __syncthreads();

  float suml = 0.f;
  for (int l = tid; l < SEQ; l += 256) {
    const uint16_t* rowp = Out + (size_t)(n * SEQ + l) * DM + h * DH;
    float acc = 0.f;
#pragma unroll
    for (int c = 0; c < 8; ++c) {
      union { uint4 v; uint16_t u[8]; } t;
      t.v = *(const uint4*)(rowp + c * 8);
#pragma unroll
      for (int j = 0; j < 8; ++j)
        acc += __uint_as_float(((uint32_t)t.u[j]) << 16) * rsl[c * 8 + j];
    }
    float e = __builtin_amdgcn_exp2f(acc * (0.125f * 1.44269504f));
    e = (mask[n * SEQ + l] > 0.f) ? e : 0.f;
    ex[l] = e;
    suml += e;
  }
#pragma unroll
  for (int off = 32; off; off >>= 1) suml += __shfl_down(suml, off, 64);
  if ((tid & 63) == 0) red[tid >> 6] = suml;
  __syncthreads();
  float inv = 1.0f / (red[0] + red[1] + red[2] + red[3]);

  int d0 = (tid & 31) * 2, ch = tid >> 5;
  float a0 = 0.f, a1 = 0.f;
  for (int l = ch * 64; l < ch * 64 + 64; ++l) {
    uint32_t pv = *(const uint32_t*)(Out + (size_t)(n * SEQ + l) * DM + h * DH + d0);
    float e = ex[l];
    a0 = fmaf(__uint_as_float(pv << 16), e, a0);
    a1 = fmaf(__uint_as_float(pv & 0xFFFF0000u), e, a1);
  }
  part[ch][d0] = a0;
  part[ch][d0 + 1] = a1;
  __syncthreads();
  if (tid < 64) {
    float s = 0.f;
#pragma unroll
    for (int c = 0; c < 8; ++c) s += part[c][tid];
    dst[n * DM + h * DH + tid] = s * inv;
  }
}

// ---------------- launch ----------------
extern "C" void kernel_launch(void* const* d_in, const int* in_sizes, int n_in,
                              void* d_out, int out_size, void* d_ws, size_t ws_size,
                              hipStream_t stream) {
  const float* tokens  = (const float*)d_in[0];
  const float* ts      = (const float*)d_in[1];
  const float* mask    = (const float*)d_in[2];
  const float* Wq      = (const float*)d_in[3];
  const float* bq      = (const float*)d_in[4];
  const float* Wk      = (const float*)d_in[5];
  const float* bk      = (const float*)d_in[6];
  const float* Wv      = (const float*)d_in[7];
  const float* bv      = (const float*)d_in[8];
  const float* Wo      = (const float*)d_in[9];
  const float* bo      = (const float*)d_in[10];
  const float* readout = (const float*)d_in[11];

  char* ws = (char*)d_ws;
  uint16_t* X    = (uint16_t*)ws;                   // 50,331,648 B ; reused as attn_out
  uint16_t* Wqkv = (uint16_t*)(ws + 50331648);      //  3,538,944 B
  uint16_t* Wob  = (uint16_t*)(ws + 53870592);      //  1,179,648 B
  float*    bqkv = (float*)   (ws + 55050240);      //      9,216 B
  uint16_t* QKV  = (uint16_t*)(ws + 55059456);      // 150,994,944 B ; reused as Out
  uint16_t* attn = X;
  uint16_t* Outb = QKV;

  k_cvt<<<12288, 256, 0, stream>>>(tokens, Wq, Wk, Wv, Wo, bq, bk, bv, X, Wqkv, Wob, bqkv);
  k_gemm_bt<<<4608, 256, 0, stream>>>(X, Wqkv, bqkv, nullptr, QKV, DM, NQKV, 18);
  k_attn<<<3072, 256, 0, stream>>>(QKV, ts, mask, attn);
  k_gemm_bt<<<1536, 256, 0, stream>>>(attn, Wob, bo, mask, Outb, DM, DM, 6);
  k_pool<<<768, 256, 0, stream>>>(Outb, mask, readout, (float*)d_out);
}

// Round 9
// 496.577 us; speedup vs baseline: 1.3311x; 1.3311x over previous
//
#include <hip/hip_runtime.h>
#include <stdint.h>

#define AS1 __attribute__((address_space(1)))
#define AS3 __attribute__((address_space(3)))

typedef __bf16 bf16x8 __attribute__((ext_vector_type(8)));   // 4 VGPRs
typedef float  f32x4  __attribute__((ext_vector_type(4)));
typedef float  f32x16 __attribute__((ext_vector_type(16)));

#define MFMA16(a, b, c) __builtin_amdgcn_mfma_f32_16x16x32_bf16((a), (b), (c), 0, 0, 0)
#define MFMA32(a, b, c) __builtin_amdgcn_mfma_f32_32x32x16_bf16((a), (b), (c), 0, 0, 0)

// ---- constants for this problem ----
#define SEQ   512
#define NBAT  64
#define DM    768
#define NH    12
#define DH    64
#define NQKV  2304
#define NTOK  (NBAT * SEQ)   // 32768
// Both GEMMs contract over K=768 -> 12 K-blocks of 64.
#define NKB   12

__device__ __forceinline__ uint16_t f2bf(float x) {          // fp32 -> bf16 RNE
  uint32_t u = __float_as_uint(x);
  return (uint16_t)((u + 0x7FFFu + ((u >> 16) & 1u)) >> 16);
}

__device__ __forceinline__ void async16(uint16_t* lds, const uint16_t* g) {
  // 16B global -> LDS direct (dest = wave-uniform base + lane*16)
  __builtin_amdgcn_global_load_lds((AS1 void*)(uintptr_t)(const void*)g,
                                   (AS3 void*)lds, 16, 0, 0);
}

// row->column XOR swizzle: conflict-free for 16/32-row MFMA fragment reads
// (verified: R5 GEMM conflicts 1.4e7 -> 0).
__device__ __forceinline__ int swz(int r) { return (r ^ (r >> 3)) & 7; }

// ---------------- merged converter + weight fragment-packing ----------------
// Packed layout: 16B chunk index ((g*NKB + kb)*4 + ks)*64 + lane holds
// B[row = g*32 + (lane&31)][k = kb*64 + ks*16 + (lane>>5)*8 .. +8) as bf16.
// A wave's per-(kb,ks) fragment load = 64 consecutive chunks = 1KB contiguous.
__global__ __launch_bounds__(256) void k_cvt(
    const float* __restrict__ tokens,
    const float* __restrict__ Wq, const float* __restrict__ Wk,
    const float* __restrict__ Wv, const float* __restrict__ Wo,
    const float* __restrict__ bq, const float* __restrict__ bk, const float* __restrict__ bv,
    uint16_t* __restrict__ X, uint16_t* __restrict__ Wqkv_pk, uint16_t* __restrict__ Wob_pk,
    float* __restrict__ bqkv) {
  int i = blockIdx.x * 256 + threadIdx.x;     // grid covers NTOK*DM/8 = 3,145,728
  {
    const float4* sp = (const float4*)tokens;
    float4 a = sp[2 * i], b = sp[2 * i + 1];
    union { uint16_t u[8]; uint4 v; } o;
    o.u[0] = f2bf(a.x); o.u[1] = f2bf(a.y); o.u[2] = f2bf(a.z); o.u[3] = f2bf(a.w);
    o.u[4] = f2bf(b.x); o.u[5] = f2bf(b.y); o.u[6] = f2bf(b.z); o.u[7] = f2bf(b.w);
    ((uint4*)X)[i] = o.v;
  }
  // Wqkv pack: 2304*768/8 = 221184 chunks
  if (i < 221184) {
    int lane = i & 63, ks = (i >> 6) & 3, kb = (i >> 8) % NKB, g = i / 3072;
    int row = g * 32 + (lane & 31);
    int k   = kb * 64 + ks * 16 + (lane >> 5) * 8;
    const float* src = (row < 768)  ? Wq + (size_t)row * 768 + k
                     : (row < 1536) ? Wk + (size_t)(row - 768) * 768 + k
                                    : Wv + (size_t)(row - 1536) * 768 + k;
    float4 a = *(const float4*)src, b = *(const float4*)(src + 4);
    union { uint16_t u[8]; uint4 v; } o;
    o.u[0] = f2bf(a.x); o.u[1] = f2bf(a.y); o.u[2] = f2bf(a.z); o.u[3] = f2bf(a.w);
    o.u[4] = f2bf(b.x); o.u[5] = f2bf(b.y); o.u[6] = f2bf(b.z); o.u[7] = f2bf(b.w);
    ((uint4*)Wqkv_pk)[i] = o.v;
  }
  // Wo pack: 768*768/8 = 73728 chunks
  if (i < 73728) {
    int lane = i & 63, ks = (i >> 6) & 3, kb = (i >> 8) % NKB, g = i / 3072;
    int row = g * 32 + (lane & 31);
    int k   = kb * 64 + ks * 16 + (lane >> 5) * 8;
    const float* src = Wo + (size_t)row * 768 + k;
    float4 a = *(const float4*)src, b = *(const float4*)(src + 4);
    union { uint16_t u[8]; uint4 v; } o;
    o.u[0] = f2bf(a.x); o.u[1] = f2bf(a.y); o.u[2] = f2bf(a.z); o.u[3] = f2bf(a.w);
    o.u[4] = f2bf(b.x); o.u[5] = f2bf(b.y); o.u[6] = f2bf(b.z); o.u[7] = f2bf(b.w);
    ((uint4*)Wob_pk)[i] = o.v;
  }
  if (i < 768) { bqkv[i] = bq[i]; bqkv[i + 768] = bk[i]; bqkv[i + 1536] = bv[i]; }
}

// ---------------- GEMM: C[M,N] = A[M,768] * B[N,768]^T + bias(col), optional *rowscale(row) ----------------
// 128x128 tile, BK=64, 4 waves (2x2 of 64x64), 32x32x16 bf16 MFMA.
// A staged in LDS (swizzled, global_load_lds). B fragments loaded from the
// fragment-packed weight array: per (kb,ks) the wave reads 1KB CONTIGUOUS
// (4 cache lines), L2-resident -> LDS traffic per block-iter 96KB -> 48KB.
// 1D grid, super-tiled: supers of 32 row-tiles x ncol col-tiles.
__global__ __launch_bounds__(256) void k_gemm_bt(
    const uint16_t* __restrict__ A, const uint16_t* __restrict__ Bpk,
    const float* __restrict__ bias, const float* __restrict__ rowscale,
    uint16_t* __restrict__ C, int ldc, int ncol) {
  __shared__ uint16_t Alds[128 * 64];   // 16 KB
  const int tid  = threadIdx.x;
  const int w    = tid >> 6, lane = tid & 63;
  const int wu   = __builtin_amdgcn_readfirstlane(w);
  const int l32  = lane & 31, kh = lane >> 5;
  const int sup  = blockIdx.x / (32 * ncol);
  const int t    = blockIdx.x % (32 * ncol);
  const int row0 = (sup * 32 + (t & 31)) * 128, col0 = (t >> 5) * 128;
  const int wrow = (w >> 1) * 64,   wcol = (w & 1) * 64;

  // packed-B base for this wave: group g0 = col0/32 + (w&1)*2; +nt advances one group.
  // group stride = NKB*4*64 chunks * 8 elems = NKB*2048 elems.
  const uint16_t* bw = Bpk + (size_t)((col0 >> 5) + (w & 1) * 2) * (NKB * 2048) + lane * 8;

  f32x16 acc[2][2] = {};
  for (int kb = 0; kb < NKB; ++kb) {
    // B fragments: 8 contiguous-per-wave 16B loads (L2 hits)
    bf16x8 bfr[4][2];
#pragma unroll
    for (int ks = 0; ks < 4; ++ks)
#pragma unroll
      for (int nt = 0; nt < 2; ++nt)
        bfr[ks][nt] = *(const bf16x8*)(bw + (size_t)nt * (NKB * 2048) + (kb * 4 + ks) * 512);
    __syncthreads();                              // prev iter's A-frag reads done
#pragma unroll
    for (int j = 0; j < 4; ++j) {                 // A: 1024 chunks
      int cid = j * 256 + w * 64 + lane;
      int r = cid >> 3, cc = cid & 7, c = cc ^ swz(r);
      async16(&Alds[(j * 256 + wu * 64) * 8],
              A + (size_t)(row0 + r) * 768 + kb * 64 + c * 8);
    }
    __syncthreads();                              // staging (and B loads) drained
#pragma unroll
    for (int ks = 0; ks < 4; ++ks) {              // 4 k-steps of 16
      bf16x8 af[2];
#pragma unroll
      for (int mt = 0; mt < 2; ++mt) {
        int r = wrow + mt * 32 + l32;
        int c = (ks * 2 + kh) ^ swz(r);
        af[mt] = *(const bf16x8*)&Alds[r * 64 + c * 8];
      }
#pragma unroll
      for (int mt = 0; mt < 2; ++mt)
#pragma unroll
        for (int nt = 0; nt < 2; ++nt)
          acc[mt][nt] = MFMA32(af[mt], bfr[ks][nt], acc[mt][nt]);
    }
  }
  // epilogue: 32x32 C/D layout: col=lane&31, row=(reg&3)+8*(reg>>2)+4*(lane>>5)
#pragma unroll
  for (int nt = 0; nt < 2; ++nt) {
    int col = col0 + wcol + nt * 32 + l32;
    float bv = bias[col];
#pragma unroll
    for (int mt = 0; mt < 2; ++mt) {
#pragma unroll
      for (int rg = 0; rg < 16; ++rg) {
        int row = row0 + wrow + mt * 32 + (rg & 3) + 8 * (rg >> 2) + 4 * kh;
        float v = acc[mt][nt][rg] + bv;
        if (rowscale) v *= rowscale[row];
        C[(size_t)row * ldc + col] = f2bf(v);
      }
    }
  }
}

// ---------------- fused attention (unchanged from R7) ----------------
__global__ __launch_bounds__(256) void k_attn(
    const uint16_t* __restrict__ QKV, const float* __restrict__ ts,
    const float* __restrict__ mask, uint16_t* __restrict__ Aout) {
  __shared__ uint16_t Klds[64 * 64];        // swizzled chunks, 8KB
  __shared__ uint16_t Vt[64 * 72];          // [d][k] padded, 9KB
  __shared__ uint16_t Plds[4][32 * 72];     // per-wave P tile, stride 72, 18KB
  __shared__ float tkl[SEQ];                // ts*c2, masked -> +3e38

  const int tid = threadIdx.x, w = tid >> 6, lane = tid & 63;
  const int wu = __builtin_amdgcn_readfirstlane(w);
  const int quad = lane >> 4, l16 = lane & 15;
  int b = blockIdx.x;
  int xcd = b & 7, i = b >> 3;
  int qt = i & 3;
  int hg = xcd * 96 + (i >> 2);             // 0..767
  int n = hg / NH, h = hg % NH;
  const int q0 = qt * 128 + w * 32;
  const size_t rowbase = (size_t)n * SEQ * NQKV;

  const float c1 = 0.125f * 1.44269504f;     // scale * log2(e)
  const float c2 = 1.44269504f / 300.0f;     // log2(e) / tau

  for (int l = tid; l < SEQ; l += 256) {
    float t = ts[n * SEQ + l] * c2;
    tkl[l] = (mask[n * SEQ + l] > 0.f) ? t : 3e38f;
  }

  // Q fragments (A-operand): A[m=lane&15][k=quad*8+j]
  bf16x8 qf[2][2];
  float tq[2][4];
#pragma unroll
  for (int qs = 0; qs < 2; ++qs) {
    int qr = q0 + qs * 16 + l16;
    const uint16_t* qp = QKV + rowbase + (size_t)qr * NQKV + h * DH;
#pragma unroll
    for (int dsp = 0; dsp < 2; ++dsp)
      qf[qs][dsp] = *(const bf16x8*)(qp + dsp * 32 + quad * 8);
#pragma unroll
    for (int rg = 0; rg < 4; ++rg)
      tq[qs][rg] = ts[n * SEQ + q0 + qs * 16 + quad * 4 + rg] * c2;
  }

  f32x4 accO[2][4] = {};
  f32x4 accL[2] = {};
  bf16x8 ones_b;
  {
    union { uint16_t u[8]; bf16x8 v; } t;
    uint16_t o = (l16 == 0) ? 0x3F80 : 0;   // bf16 1.0 in column 0 only
#pragma unroll
    for (int j = 0; j < 8; ++j) t.u[j] = o;
    ones_b = t.v;
  }
  uint16_t* Pw = &Plds[w][0];

  for (int k0 = 0; k0 < SEQ; k0 += 64) {
    __syncthreads();
    // stage K rows (row-major 64x64, swz-swizzled) via global_load_lds
#pragma unroll
    for (int j = 0; j < 2; ++j) {
      int cid = j * 256 + w * 64 + lane;      // 0..511
      int r = cid >> 3, cc = cid & 7, c = cc ^ swz(r);
      const uint16_t* g = QKV + rowbase + (size_t)(k0 + r) * NQKV + DM + h * DH + c * 8;
      async16(&Klds[(j * 256 + wu * 64) * 8], g);
    }
    // stage V transposed: Vt[d][k]
    {
      int r = tid & 63, db = (tid >> 6) * 16;
      const uint16_t* g = QKV + rowbase + (size_t)(k0 + r) * NQKV + 2 * DM + h * DH + db;
      union { uint4 v; uint16_t u[8]; } a0, a1;
      a0.v = *(const uint4*)g;
      a1.v = *(const uint4*)(g + 8);
#pragma unroll
      for (int j = 0; j < 8; ++j) Vt[(db + j) * 72 + r] = a0.u[j];
#pragma unroll
      for (int j = 0; j < 8; ++j) Vt[(db + 8 + j) * 72 + r] = a1.u[j];
    }
    __syncthreads();

#pragma unroll
    for (int kt = 0; kt < 2; ++kt) {
      // S = Q K^T over this 32-col k-tile; columns interleaved: n -> k = 2*(lane&15)+ksu
      f32x4 s[2][2] = {};
#pragma unroll
      for (int dsp = 0; dsp < 2; ++dsp) {
        bf16x8 kf[2];
#pragma unroll
        for (int ksu = 0; ksu < 2; ++ksu) {
          int r = kt * 32 + 2 * l16 + ksu;
          int c = (dsp * 4 + quad) ^ swz(r);
          kf[ksu] = *(const bf16x8*)&Klds[r * 64 + c * 8];
        }
#pragma unroll
        for (int qs = 0; qs < 2; ++qs)
#pragma unroll
          for (int ksu = 0; ksu < 2; ++ksu)
            s[qs][ksu] = MFMA16(qf[qs][dsp], kf[ksu], s[qs][ksu]);
      }
      // bias + exp + pack to bf16 pairs -> Plds[q][k] (natural k order)
      float tk0 = tkl[k0 + kt * 32 + 2 * l16];
      float tk1 = tkl[k0 + kt * 32 + 2 * l16 + 1];
#pragma unroll
      for (int qs = 0; qs < 2; ++qs) {
#pragma unroll
        for (int rg = 0; rg < 4; ++rg) {
          float d0 = fabsf(tq[qs][rg] - tk0);   // v_sub; abs/neg ride as fma modifiers
          float d1 = fabsf(tq[qs][rg] - tk1);
          float p0 = __builtin_amdgcn_exp2f(fmaf(s[qs][0][rg], c1, -d0));
          float p1 = __builtin_amdgcn_exp2f(fmaf(s[qs][1][rg], c1, -d1));
          uint32_t u = (__float_as_uint(p0) >> 16) | (__float_as_uint(p1) & 0xFFFF0000u);
          *(uint32_t*)(Pw + (qs * 16 + quad * 4 + rg) * 72 + kt * 32 + 2 * l16) = u;
        }
      }
      // PV (+ ones column for row-sums). Wave-private LDS: per-wave in-order, no barrier.
      bf16x8 vb[4];
#pragma unroll
      for (int dt = 0; dt < 4; ++dt)
        vb[dt] = *(const bf16x8*)&Vt[(dt * 16 + l16) * 72 + kt * 32 + quad * 8];
#pragma unroll
      for (int qs = 0; qs < 2; ++qs) {
        bf16x8 pa = *(const bf16x8*)(Pw + (qs * 16 + l16) * 72 + kt * 32 + quad * 8);
#pragma unroll
        for (int dt = 0; dt < 4; ++dt)
          accO[qs][dt] = MFMA16(pa, vb[dt], accO[qs][dt]);
        accL[qs] = MFMA16(pa, ones_b, accL[qs]);
      }
    }
  }
  // epilogue: O = accO / l ; l lives in column 0 (lane quad*16) of accL
#pragma unroll
  for (int qs = 0; qs < 2; ++qs) {
    float inv[4];
#pragma unroll
    for (int rg = 0; rg < 4; ++rg) {
      float lv = __shfl(accL[qs][rg], lane & 48, 64);
      inv[rg] = 1.0f / lv;
    }
#pragma unroll
    for (int dt = 0; dt < 4; ++dt) {
#pragma unroll
      for (int rg = 0; rg < 4; ++rg) {
        int qr = q0 + qs * 16 + quad * 4 + rg;
        float v = accO[qs][dt][rg] * inv[rg];
        Aout[(size_t)(n * SEQ + qr) * DM + h * DH + dt * 16 + l16] = f2bf(v);
      }
    }
  }
}

// ---------------- readout pooling ----------------
__global__ __launch_bounds__(256) void k_pool(
    const uint16_t* __restrict__ Out, const float* __restrict__ mask,
    const float* __restrict__ readout, float* __restrict__ dst) {
  __shared__ float rsl[64];
  __shared__ float ex[SEQ];
  __shared__ float red[4];
  __shared__ float part[8][64];
  int b = blockIdx.x;
  int n = b / NH, h = b % NH;
  int tid = threadIdx.x;
  if (tid < 64) rsl[tid] = readout[h * DH + tid];
  __syncthreads();

  float suml = 0.f;
  for (int l = tid; l < SEQ; l += 256) {
    const uint16_t* rowp = Out + (size_t)(n * SEQ + l) * DM + h * DH;
    float acc = 0.f;
#pragma unroll
    for (int c = 0; c < 8; ++c) {
      union { uint4 v; uint16_t u[8]; } t;
      t.v = *(const uint4*)(rowp + c * 8);
#pragma unroll
      for (int j = 0; j < 8; ++j)
        acc += __uint_as_float(((uint32_t)t.u[j]) << 16) * rsl[c * 8 + j];
    }
    float e = __builtin_amdgcn_exp2f(acc * (0.125f * 1.44269504f));
    e = (mask[n * SEQ + l] > 0.f) ? e : 0.f;
    ex[l] = e;
    suml += e;
  }
#pragma unroll
  for (int off = 32; off; off >>= 1) suml += __shfl_down(suml, off, 64);
  if ((tid & 63) == 0) red[tid >> 6] = suml;
  __syncthreads();
  float inv = 1.0f / (red[0] + red[1] + red[2] + red[3]);

  int d0 = (tid & 31) * 2, ch = tid >> 5;
  float a0 = 0.f, a1 = 0.f;
  for (int l = ch * 64; l < ch * 64 + 64; ++l) {
    uint32_t pv = *(const uint32_t*)(Out + (size_t)(n * SEQ + l) * DM + h * DH + d0);
    float e = ex[l];
    a0 = fmaf(__uint_as_float(pv << 16), e, a0);
    a1 = fmaf(__uint_as_float(pv & 0xFFFF0000u), e, a1);
  }
  part[ch][d0] = a0;
  part[ch][d0 + 1] = a1;
  __syncthreads();
  if (tid < 64) {
    float s = 0.f;
#pragma unroll
    for (int c = 0; c < 8; ++c) s += part[c][tid];
    dst[n * DM + h * DH + tid] = s * inv;
  }
}

// ---------------- launch ----------------
extern "C" void kernel_launch(void* const* d_in, const int* in_sizes, int n_in,
                              void* d_out, int out_size, void* d_ws, size_t ws_size,
                              hipStream_t stream) {
  const float* tokens  = (const float*)d_in[0];
  const float* ts      = (const float*)d_in[1];
  const float* mask    = (const float*)d_in[2];
  const float* Wq      = (const float*)d_in[3];
  const float* bq      = (const float*)d_in[4];
  const float* Wk      = (const float*)d_in[5];
  const float* bk      = (const float*)d_in[6];
  const float* Wv      = (const float*)d_in[7];
  const float* bv      = (const float*)d_in[8];
  const float* Wo      = (const float*)d_in[9];
  const float* bo      = (const float*)d_in[10];
  const float* readout = (const float*)d_in[11];

  char* ws = (char*)d_ws;
  uint16_t* X    = (uint16_t*)ws;                   // 50,331,648 B ; reused as attn_out
  uint16_t* Wqkv = (uint16_t*)(ws + 50331648);      //  3,538,944 B (packed)
  uint16_t* Wob  = (uint16_t*)(ws + 53870592);      //  1,179,648 B (packed)
  float*    bqkv = (float*)   (ws + 55050240);      //      9,216 B
  uint16_t* QKV  = (uint16_t*)(ws + 55059456);      // 150,994,944 B ; reused as Out
  uint16_t* attn = X;
  uint16_t* Outb = QKV;

  k_cvt<<<12288, 256, 0, stream>>>(tokens, Wq, Wk, Wv, Wo, bq, bk, bv, X, Wqkv, Wob, bqkv);
  k_gemm_bt<<<4608, 256, 0, stream>>>(X, Wqkv, bqkv, nullptr, QKV, NQKV, 18);
  k_attn<<<3072, 256, 0, stream>>>(QKV, ts, mask, attn);
  k_gemm_bt<<<1536, 256, 0, stream>>>(attn, Wob, bo, mask, Outb, DM, 6);
  k_pool<<<768, 256, 0, stream>>>(Outb, mask, readout, (float*)d_out);
}